// Round 1
// baseline (172.688 us; speedup 1.0000x reference)
//
#include <hip/hip_runtime.h>
#include <math.h>

#define PI_F 3.14159265358979323846f

// Fourier (trigonometric) interpolation, closed form via Dirichlet kernels:
//   ynew = (c1^T Y c2 - s1^T Y s2) / 4096
// with per-dim vectors (t = x - n/64):
//   s[n] = sin(64*pi*t) = (-1)^n * sin(64*pi*x)
//   c[n] = sin(64*pi*t) * cot(pi*t)
// Nearest-grid entry n* recomputed via exact delta to avoid cancellation.

__global__ __launch_bounds__(256, 2)
void fourier_interp_kernel(const float* __restrict__ y,
                           const float* __restrict__ xnew,
                           float* __restrict__ out)
{
    __shared__ float  Ylds[64 * 64];   // 16 KB: Y for this batch
    __shared__ float2 tab[64];         // (cos(pi*n/64), sin(pi*n/64))

    const int tid  = threadIdx.x;
    const int b    = blockIdx.x >> 6;   // 64 blocks per batch
    const int tile = blockIdx.x & 63;

    // stage Y[b] into LDS (coalesced float4), 4096 floats
    {
        const float4* src = (const float4*)(y + (b << 12));
        float4* dst = (float4*)Ylds;
#pragma unroll
        for (int i = 0; i < 4; ++i)
            dst[tid + 256 * i] = src[tid + 256 * i];
    }
    if (tid < 64) {
        float sn, cn;
        sincosf(PI_F * (float)tid * (1.0f / 64.0f), &sn, &cn);
        tab[tid] = make_float2(cn, sn);
    }
    __syncthreads();

    const int pid = (b << 14) + (tile << 8) + tid;
    const float2 xv = ((const float2*)xnew)[pid];

    // ---- per-dim setup ----
    float sx1, cx1, s64_1, cfix1; int nstar1;
    float sx2, cx2, s64_2, cfix2; int nstar2;
    {
        const float x = xv.x;
        sincosf(PI_F * x, &sx1, &cx1);
        const float g = x * 64.0f;        // exact
        const float j = rintf(g);
        const float f = g - j;            // exact (Sterbenz), in [-0.5, 0.5]
        const int  ji = (int)j;           // 0..64
        const float sf = sinf(PI_F * f);
        s64_1  = (ji & 1) ? -sf : sf;
        nstar1 = ji & 63;
        const float delta = x - j * 0.015625f;   // exact
        cfix1 = (f == 0.0f) ? 64.0f
                            : sf * cosf(PI_F * delta) / sinf(PI_F * delta);
    }
    {
        const float x = xv.y;
        sincosf(PI_F * x, &sx2, &cx2);
        const float g = x * 64.0f;
        const float j = rintf(g);
        const float f = g - j;
        const int  ji = (int)j;
        const float sf = sinf(PI_F * f);
        s64_2  = (ji & 1) ? -sf : sf;
        nstar2 = ji & 63;
        const float delta = x - j * 0.015625f;
        cfix2 = (f == 0.0f) ? 64.0f
                            : sf * cosf(PI_F * delta) / sinf(PI_F * delta);
    }

    // ---- phase 1: u_c[n2] = sum_n1 c1[n1]*Y[n1][n2], u_s likewise ----
    float uc[64], us[64];
#pragma unroll
    for (int i = 0; i < 64; ++i) { uc[i] = 0.0f; us[i] = 0.0f; }

    for (int h = 0; h < 32; ++h) {
        const int n1 = h << 1;
        const float2 t0 = tab[n1];
        const float2 t1 = tab[n1 + 1];

        // even row: sign = +1
        const float st_e = sx1 * t0.x - cx1 * t0.y;   // sin(pi*(x - n1/64))
        const float ct_e = cx1 * t0.x + sx1 * t0.y;   // cos(pi*(x - n1/64))
        const float s1e  = s64_1;
        float c1e = s1e * ct_e * __builtin_amdgcn_rcpf(st_e);
        if (n1 == nstar1) c1e = cfix1;

        // odd row: sign = -1
        const float st_o = sx1 * t1.x - cx1 * t1.y;
        const float ct_o = cx1 * t1.x + sx1 * t1.y;
        const float s1o  = -s64_1;
        float c1o = s1o * ct_o * __builtin_amdgcn_rcpf(st_o);
        if (n1 + 1 == nstar1) c1o = cfix1;

        const float4* row0 = (const float4*)(Ylds + (n1 << 6));
        const float4* row1 = (const float4*)(Ylds + ((n1 + 1) << 6));
#pragma unroll
        for (int q = 0; q < 16; ++q) {
            const float4 v0 = row0[q];
            const float4 v1 = row1[q];
            uc[4*q+0] = fmaf(c1e, v0.x, fmaf(c1o, v1.x, uc[4*q+0]));
            uc[4*q+1] = fmaf(c1e, v0.y, fmaf(c1o, v1.y, uc[4*q+1]));
            uc[4*q+2] = fmaf(c1e, v0.z, fmaf(c1o, v1.z, uc[4*q+2]));
            uc[4*q+3] = fmaf(c1e, v0.w, fmaf(c1o, v1.w, uc[4*q+3]));
            us[4*q+0] = fmaf(s1e, v0.x, fmaf(s1o, v1.x, us[4*q+0]));
            us[4*q+1] = fmaf(s1e, v0.y, fmaf(s1o, v1.y, us[4*q+1]));
            us[4*q+2] = fmaf(s1e, v0.z, fmaf(s1o, v1.z, us[4*q+2]));
            us[4*q+3] = fmaf(s1e, v0.w, fmaf(s1o, v1.w, us[4*q+3]));
        }
    }

    // ---- phase 2: acc = sum_n2 c2[n2]*uc[n2] - s2[n2]*us[n2] ----
    float acc = 0.0f;
#pragma unroll
    for (int h = 0; h < 32; ++h) {
        const int n2 = h << 1;
        const float2 t0 = tab[n2];
        const float2 t1 = tab[n2 + 1];

        const float st_e = sx2 * t0.x - cx2 * t0.y;
        const float ct_e = cx2 * t0.x + sx2 * t0.y;
        float c2e = s64_2 * ct_e * __builtin_amdgcn_rcpf(st_e);
        if (n2 == nstar2) c2e = cfix2;

        const float st_o = sx2 * t1.x - cx2 * t1.y;
        const float ct_o = cx2 * t1.x + sx2 * t1.y;
        float c2o = -s64_2 * ct_o * __builtin_amdgcn_rcpf(st_o);
        if (n2 + 1 == nstar2) c2o = cfix2;

        acc = fmaf(c2e, uc[n2], acc);
        acc = fmaf(c2o, uc[n2 + 1], acc);
        // s2e = s64_2, s2o = -s64_2  =>  -(s2e*us[e] + s2o*us[o]) = -s64_2*(us[e]-us[o])
        acc = fmaf(-s64_2, us[n2] - us[n2 + 1], acc);
    }

    out[pid] = acc * (1.0f / 4096.0f);
}

extern "C" void kernel_launch(void* const* d_in, const int* in_sizes, int n_in,
                              void* d_out, int out_size, void* d_ws, size_t ws_size,
                              hipStream_t stream)
{
    const float* y    = (const float*)d_in[0];   // [32, 64, 64]
    const float* xnew = (const float*)d_in[1];   // [32, 128, 128, 2]
    float* out        = (float*)d_out;           // [32, 128, 128]

    // 32 batches * 64 tiles of 256 points = 2048 blocks
    fourier_interp_kernel<<<2048, 256, 0, stream>>>(y, xnew, out);
}

// Round 2
// 153.742 us; speedup vs baseline: 1.1232x; 1.1232x over previous
//
#include <hip/hip_runtime.h>
#include <math.h>

#define PI_F 3.14159265358979323846f

// Fourier (trigonometric) interpolation, closed form via Dirichlet kernels:
//   ynew*4096 = c1^T Y c2 - s1^T Y s2
// Key identities:
//   s[n] = sin(64*pi*(x - n/64)) = (-1)^n * sin(64*pi*x)  (exact, smooth)
//     => s1^T Y s2 = s64_1*s64_2 * W,  W = sum (-1)^(n1+n2) Y[n1,n2]  (per-batch scalar)
//   c[n] = s[n]*cot(pi*(x-n/64)); nearest-grid entry recomputed via exact delta.
// Each thread carries 4 points so every broadcast LDS float4 feeds 16 FMAs.

__global__ __launch_bounds__(256, 2)
void fourier_interp_kernel(const float* __restrict__ y,
                           const float* __restrict__ xnew,
                           float* __restrict__ out)
{
    __shared__ float  Ylds[4096];   // 16 KB: Y for this batch
    __shared__ float2 tab[64];      // (cos(pi*n/64), sin(pi*n/64))
    __shared__ float  Wpart[4];

    const int tid   = threadIdx.x;
    const int batch = blockIdx.x >> 4;   // 16 blocks per batch
    const int seg   = blockIdx.x & 15;   // 1024 points per block

    // ---- stage Y[batch] into LDS, fold in signed sum for W ----
    float wsum = 0.0f;
    {
        const float4* src = (const float4*)(y + (batch << 12));
        float4* dst = (float4*)Ylds;
#pragma unroll
        for (int i = 0; i < 4; ++i) {
            const int idx = tid + (i << 8);
            const float4 v = src[idx];
            dst[idx] = v;
            const float sv = (v.x - v.y) + (v.z - v.w);   // (+,-,+,-) over n2
            wsum += ((idx >> 4) & 1) ? -sv : sv;          // (-1)^n1, n1 = idx/16
        }
    }
#pragma unroll
    for (int off = 32; off > 0; off >>= 1)
        wsum += __shfl_down(wsum, off, 64);
    if ((tid & 63) == 0) Wpart[tid >> 6] = wsum;

    if (tid < 64) {
        float sn, cn;
        sincosf(PI_F * (float)tid * (1.0f / 64.0f), &sn, &cn);
        tab[tid] = make_float2(cn, sn);
    }
    __syncthreads();

    const float W = (Wpart[0] + Wpart[1]) + (Wpart[2] + Wpart[3]);

    // ---- per-point setup (4 points per thread, stride 256) ----
    const int pbase = (batch << 14) + (seg << 10) + tid;
    float sx1[4], cx1[4], s641[4], cf1[4];
    float sx2[4], cx2[4], s642[4], cf2[4];
    int   ns1[4], ns2[4];
#pragma unroll
    for (int k = 0; k < 4; ++k) {
        const float2 xv = ((const float2*)xnew)[pbase + (k << 8)];
        {
            const float x = xv.x;
            sincosf(PI_F * x, &sx1[k], &cx1[k]);
            const float g = x * 64.0f;          // exact
            const float j = rintf(g);
            const float f = g - j;              // exact (Sterbenz)
            const int  ji = (int)j;
            const float sf = sinf(PI_F * f);
            s641[k] = (ji & 1) ? -sf : sf;
            ns1[k]  = ji & 63;
            const float d = x - j * 0.015625f;  // exact
            cf1[k] = (f == 0.0f) ? 64.0f
                                 : sf * cosf(PI_F * d) / sinf(PI_F * d);
        }
        {
            const float x = xv.y;
            sincosf(PI_F * x, &sx2[k], &cx2[k]);
            const float g = x * 64.0f;
            const float j = rintf(g);
            const float f = g - j;
            const int  ji = (int)j;
            const float sf = sinf(PI_F * f);
            s642[k] = (ji & 1) ? -sf : sf;
            ns2[k]  = ji & 63;
            const float d = x - j * 0.015625f;
            cf2[k] = (f == 0.0f) ? 64.0f
                                 : sf * cosf(PI_F * d) / sinf(PI_F * d);
        }
    }

    float acc[4] = {0.0f, 0.0f, 0.0f, 0.0f};

    // ---- bilinear form, n2 tiled by 32 so uc fits in 128 VGPRs ----
    for (int tile = 0; tile < 2; ++tile) {
        float uc[4][32];
#pragma unroll
        for (int k = 0; k < 4; ++k)
#pragma unroll
            for (int j = 0; j < 32; ++j) uc[k][j] = 0.0f;

#pragma unroll 2
        for (int n1 = 0; n1 < 64; ++n1) {
            const float2 tb = tab[n1];
            float cc[4];
#pragma unroll
            for (int k = 0; k < 4; ++k) {
                const float st = sx1[k] * tb.x - cx1[k] * tb.y;  // sin(pi*(x-n/64))
                const float ct = cx1[k] * tb.x + sx1[k] * tb.y;  // cos(pi*(x-n/64))
                const float s  = (n1 & 1) ? -s641[k] : s641[k];
                float c = s * ct * __builtin_amdgcn_rcpf(st);
                if (n1 == ns1[k]) c = cf1[k];
                cc[k] = c;
            }
            const float4* row = (const float4*)(Ylds + (n1 << 6) + (tile << 5));
#pragma unroll
            for (int q = 0; q < 8; ++q) {
                const float4 v = row[q];
#pragma unroll
                for (int k = 0; k < 4; ++k) {
                    uc[k][4*q+0] = fmaf(cc[k], v.x, uc[k][4*q+0]);
                    uc[k][4*q+1] = fmaf(cc[k], v.y, uc[k][4*q+1]);
                    uc[k][4*q+2] = fmaf(cc[k], v.z, uc[k][4*q+2]);
                    uc[k][4*q+3] = fmaf(cc[k], v.w, uc[k][4*q+3]);
                }
            }
        }

        // consume this tile's uc with dim-2 coefficients
#pragma unroll 4
        for (int j = 0; j < 32; ++j) {
            const int n2 = (tile << 5) + j;
            const float2 tb = tab[n2];
#pragma unroll
            for (int k = 0; k < 4; ++k) {
                const float st = sx2[k] * tb.x - cx2[k] * tb.y;
                const float ct = cx2[k] * tb.x + sx2[k] * tb.y;
                const float s  = (n2 & 1) ? -s642[k] : s642[k];
                float c = s * ct * __builtin_amdgcn_rcpf(st);
                if (n2 == ns2[k]) c = cf2[k];
                acc[k] = fmaf(c, uc[k][j], acc[k]);
            }
        }
    }

    // ---- subtract rank-1 sine term, normalize, store ----
#pragma unroll
    for (int k = 0; k < 4; ++k) {
        const float r = acc[k] - s641[k] * s642[k] * W;
        out[pbase + (k << 8)] = r * (1.0f / 4096.0f);
    }
}

extern "C" void kernel_launch(void* const* d_in, const int* in_sizes, int n_in,
                              void* d_out, int out_size, void* d_ws, size_t ws_size,
                              hipStream_t stream)
{
    const float* y    = (const float*)d_in[0];   // [32, 64, 64]
    const float* xnew = (const float*)d_in[1];   // [32, 128, 128, 2]
    float* out        = (float*)d_out;           // [32, 128, 128]

    // 32 batches * 16 blocks of 1024 points (4 per thread) = 512 blocks
    fourier_interp_kernel<<<512, 256, 0, stream>>>(y, xnew, out);
}

// Round 3
// 153.227 us; speedup vs baseline: 1.1270x; 1.0034x over previous
//
#include <hip/hip_runtime.h>
#include <math.h>

#define PI_F 3.14159265358979323846f

// Fourier (trigonometric) interpolation, closed form via Dirichlet kernels:
//   ynew*4096 = c1^T Y c2 - s641*s642*W
//   W = sum (-1)^(n1+n2) Y[n1,n2]  (per-batch scalar, exact rank-1 sine term)
//   c[n] = sin(64*pi*(x-n/64)) * cot(pi*(x-n/64)); nearest-grid entry
//   recomputed via exact delta (Sterbenz) to kill cancellation.
//
// Register budget is the binding constraint (round 2 spilled 340 MB to
// scratch): 2 points/thread, n2 tiled by 32 -> uc[2][32]=64 acc VGPRs,
// ~105 total, fits the 128-VGPR cap at 2 waves/SIMD. Every broadcast
// ds_read_b128 feeds 8 FMAs.

__global__ __launch_bounds__(256, 2)
void fourier_interp_kernel(const float* __restrict__ y,
                           const float* __restrict__ xnew,
                           float* __restrict__ out)
{
    __shared__ float  Ylds[4096];   // 16 KB: Y for this batch
    __shared__ float2 tab[64];      // (cos(pi*n/64), sin(pi*n/64))
    __shared__ float  Wpart[4];

    const int tid   = threadIdx.x;
    const int batch = blockIdx.x >> 5;   // 32 blocks per batch
    const int seg   = blockIdx.x & 31;   // 512 points per block

    // ---- stage Y[batch] into LDS, fold in signed sum for W ----
    float wsum = 0.0f;
    {
        const float4* src = (const float4*)(y + (batch << 12));
        float4* dst = (float4*)Ylds;
#pragma unroll
        for (int i = 0; i < 4; ++i) {
            const int idx = tid + (i << 8);
            const float4 v = src[idx];
            dst[idx] = v;
            const float sv = (v.x - v.y) + (v.z - v.w);   // (+,-,+,-) over n2
            wsum += ((idx >> 4) & 1) ? -sv : sv;          // (-1)^n1, n1 = idx/16
        }
    }
#pragma unroll
    for (int off = 32; off > 0; off >>= 1)
        wsum += __shfl_down(wsum, off, 64);
    if ((tid & 63) == 0) Wpart[tid >> 6] = wsum;

    if (tid < 64) {
        float sn, cn;
        sincosf(PI_F * (float)tid * (1.0f / 64.0f), &sn, &cn);
        tab[tid] = make_float2(cn, sn);
    }
    __syncthreads();

    const float W = (Wpart[0] + Wpart[1]) + (Wpart[2] + Wpart[3]);

    // ---- per-point setup (2 points per thread, stride 256) ----
    const int pbase = (batch << 14) + (seg << 9) + tid;
    float sx1[2], cx1[2], s641[2], cf1[2];
    float sx2[2], cx2[2], s642[2], cf2[2];
    int   ns1[2], ns2[2];
#pragma unroll
    for (int k = 0; k < 2; ++k) {
        const float2 xv = ((const float2*)xnew)[pbase + (k << 8)];
        {
            const float x = xv.x;
            sincosf(PI_F * x, &sx1[k], &cx1[k]);
            const float g = x * 64.0f;          // exact
            const float j = rintf(g);
            const float f = g - j;              // exact (Sterbenz)
            const int  ji = (int)j;
            const float sf = sinf(PI_F * f);
            s641[k] = (ji & 1) ? -sf : sf;
            ns1[k]  = ji & 63;
            const float d = x - j * 0.015625f;  // exact
            cf1[k] = (f == 0.0f) ? 64.0f
                                 : sf * cosf(PI_F * d) / sinf(PI_F * d);
        }
        {
            const float x = xv.y;
            sincosf(PI_F * x, &sx2[k], &cx2[k]);
            const float g = x * 64.0f;
            const float j = rintf(g);
            const float f = g - j;
            const int  ji = (int)j;
            const float sf = sinf(PI_F * f);
            s642[k] = (ji & 1) ? -sf : sf;
            ns2[k]  = ji & 63;
            const float d = x - j * 0.015625f;
            cf2[k] = (f == 0.0f) ? 64.0f
                                 : sf * cosf(PI_F * d) / sinf(PI_F * d);
        }
    }

    float acc[2] = {0.0f, 0.0f};

    // ---- bilinear form, n2 tiled by 32 so uc fits in 64 VGPRs ----
#pragma unroll 1
    for (int tile = 0; tile < 2; ++tile) {
        float uc[2][32];
#pragma unroll
        for (int k = 0; k < 2; ++k)
#pragma unroll
            for (int j = 0; j < 32; ++j) uc[k][j] = 0.0f;

#pragma unroll 1
        for (int h = 0; h < 16; ++h) {
#pragma unroll
            for (int nn = 0; nn < 4; ++nn) {
                const int n1 = (h << 2) + nn;    // parity of n1 == parity of nn
                const float2 tb = tab[n1];
                float cc[2];
#pragma unroll
                for (int k = 0; k < 2; ++k) {
                    const float st = sx1[k] * tb.x - cx1[k] * tb.y;  // sin(pi*(x-n/64))
                    const float ct = cx1[k] * tb.x + sx1[k] * tb.y;  // cos(pi*(x-n/64))
                    const float s  = (nn & 1) ? -s641[k] : s641[k];
                    float c = s * ct * __builtin_amdgcn_rcpf(st);
                    if (n1 == ns1[k]) c = cf1[k];
                    cc[k] = c;
                }
                const float4* row = (const float4*)(Ylds + (n1 << 6) + (tile << 5));
#pragma unroll
                for (int q = 0; q < 8; ++q) {
                    const float4 v = row[q];
#pragma unroll
                    for (int k = 0; k < 2; ++k) {
                        uc[k][4*q+0] = fmaf(cc[k], v.x, uc[k][4*q+0]);
                        uc[k][4*q+1] = fmaf(cc[k], v.y, uc[k][4*q+1]);
                        uc[k][4*q+2] = fmaf(cc[k], v.z, uc[k][4*q+2]);
                        uc[k][4*q+3] = fmaf(cc[k], v.w, uc[k][4*q+3]);
                    }
                }
            }
        }

        // consume this tile's uc with dim-2 coefficients
#pragma unroll 2
        for (int j = 0; j < 32; ++j) {
            const int n2 = (tile << 5) + j;
            const float2 tb = tab[n2];
#pragma unroll
            for (int k = 0; k < 2; ++k) {
                const float st = sx2[k] * tb.x - cx2[k] * tb.y;
                const float ct = cx2[k] * tb.x + sx2[k] * tb.y;
                const float s  = (n2 & 1) ? -s642[k] : s642[k];
                float c = s * ct * __builtin_amdgcn_rcpf(st);
                if (n2 == ns2[k]) c = cf2[k];
                acc[k] = fmaf(c, uc[k][j], acc[k]);
            }
        }
    }

    // ---- subtract rank-1 sine term, normalize, store ----
#pragma unroll
    for (int k = 0; k < 2; ++k) {
        const float r = acc[k] - s641[k] * s642[k] * W;
        out[pbase + (k << 8)] = r * (1.0f / 4096.0f);
    }
}

extern "C" void kernel_launch(void* const* d_in, const int* in_sizes, int n_in,
                              void* d_out, int out_size, void* d_ws, size_t ws_size,
                              hipStream_t stream)
{
    const float* y    = (const float*)d_in[0];   // [32, 64, 64]
    const float* xnew = (const float*)d_in[1];   // [32, 128, 128, 2]
    float* out        = (float*)d_out;           // [32, 128, 128]

    // 32 batches * 32 blocks of 512 points (2 per thread) = 1024 blocks
    fourier_interp_kernel<<<1024, 256, 0, stream>>>(y, xnew, out);
}

// Round 4
// 129.463 us; speedup vs baseline: 1.3339x; 1.1836x over previous
//
#include <hip/hip_runtime.h>
#include <math.h>

#define PI_F 3.14159265358979323846f

// Fourier (trigonometric) interpolation, closed form via Dirichlet kernels:
//   ynew*4096 = c1^T Y c2 - s641*s642*W
//   W = sum (-1)^(n1+n2) Y[n1,n2]  (per-batch scalar, exact rank-1 sine term)
//   c[n] = sin(64*pi*(x-n/64)) * cot(pi*(x-n/64)); nearest-grid entry
//   recomputed via exact delta (Sterbenz) to kill cancellation.
//
// CRITICAL lesson from rounds 2/3: every access to the accumulator array
// uc[][] must use a compile-time-constant index. A partially-unrolled
// consume loop dynamically indexes uc -> the array is allocated to scratch
// -> 200+ MB of HBM spill traffic. ALL loops touching uc are fully unrolled.

__global__ __launch_bounds__(256, 2)
void fourier_interp_kernel(const float* __restrict__ y,
                           const float* __restrict__ xnew,
                           float* __restrict__ out)
{
    __shared__ float  Ylds[4096];   // 16 KB: Y for this batch
    __shared__ float2 tab[64];      // (cos(pi*n/64), sin(pi*n/64))
    __shared__ float  Wpart[4];

    const int tid   = threadIdx.x;
    const int batch = blockIdx.x >> 5;   // 32 blocks per batch
    const int seg   = blockIdx.x & 31;   // 512 points per block

    // ---- stage Y[batch] into LDS, fold in signed sum for W ----
    float wsum = 0.0f;
    {
        const float4* src = (const float4*)(y + (batch << 12));
        float4* dst = (float4*)Ylds;
#pragma unroll
        for (int i = 0; i < 4; ++i) {
            const int idx = tid + (i << 8);
            const float4 v = src[idx];
            dst[idx] = v;
            const float sv = (v.x - v.y) + (v.z - v.w);   // (+,-,+,-) over n2
            wsum += ((idx >> 4) & 1) ? -sv : sv;          // (-1)^n1, n1 = idx/16
        }
    }
#pragma unroll
    for (int off = 32; off > 0; off >>= 1)
        wsum += __shfl_down(wsum, off, 64);
    if ((tid & 63) == 0) Wpart[tid >> 6] = wsum;

    if (tid < 64) {
        float sn, cn;
        sincosf(PI_F * (float)tid * (1.0f / 64.0f), &sn, &cn);
        tab[tid] = make_float2(cn, sn);
    }
    __syncthreads();

    const float W = (Wpart[0] + Wpart[1]) + (Wpart[2] + Wpart[3]);

    // ---- per-point setup (2 points per thread, stride 256) ----
    const int pbase = (batch << 14) + (seg << 9) + tid;
    float sx1[2], cx1[2], s641[2], cf1[2];
    float sx2[2], cx2[2], s642[2], cf2[2];
    int   ns1[2], ns2[2];
#pragma unroll
    for (int k = 0; k < 2; ++k) {
        const float2 xv = ((const float2*)xnew)[pbase + (k << 8)];
        {
            const float x = xv.x;
            sincosf(PI_F * x, &sx1[k], &cx1[k]);
            const float g = x * 64.0f;          // exact
            const float j = rintf(g);
            const float f = g - j;              // exact (Sterbenz)
            const int  ji = (int)j;
            const float sf = sinf(PI_F * f);
            s641[k] = (ji & 1) ? -sf : sf;
            ns1[k]  = ji & 63;
            const float d = x - j * 0.015625f;  // exact
            cf1[k] = (f == 0.0f) ? 64.0f
                                 : sf * cosf(PI_F * d) / sinf(PI_F * d);
        }
        {
            const float x = xv.y;
            sincosf(PI_F * x, &sx2[k], &cx2[k]);
            const float g = x * 64.0f;
            const float j = rintf(g);
            const float f = g - j;
            const int  ji = (int)j;
            const float sf = sinf(PI_F * f);
            s642[k] = (ji & 1) ? -sf : sf;
            ns2[k]  = ji & 63;
            const float d = x - j * 0.015625f;
            cf2[k] = (f == 0.0f) ? 64.0f
                                 : sf * cosf(PI_F * d) / sinf(PI_F * d);
        }
    }

    float acc[2] = {0.0f, 0.0f};

    // ---- bilinear form, n2 tiled by 32: uc[2][32] = 64 VGPRs, all
    //      accesses via constant indices (see CRITICAL note above) ----
#pragma unroll 1
    for (int tile = 0; tile < 2; ++tile) {
        float uc[2][32];
#pragma unroll
        for (int k = 0; k < 2; ++k)
#pragma unroll
            for (int j = 0; j < 32; ++j) uc[k][j] = 0.0f;

#pragma unroll 1
        for (int h = 0; h < 16; ++h) {
#pragma unroll
            for (int nn = 0; nn < 4; ++nn) {
                const int n1 = (h << 2) + nn;    // parity of n1 == parity of nn
                const float2 tb = tab[n1];
                float cc[2];
#pragma unroll
                for (int k = 0; k < 2; ++k) {
                    const float st = sx1[k] * tb.x - cx1[k] * tb.y;  // sin(pi*(x-n/64))
                    const float ct = cx1[k] * tb.x + sx1[k] * tb.y;  // cos(pi*(x-n/64))
                    const float s  = (nn & 1) ? -s641[k] : s641[k];
                    float c = s * ct * __builtin_amdgcn_rcpf(st);
                    if (n1 == ns1[k]) c = cf1[k];
                    cc[k] = c;
                }
                const float4* row = (const float4*)(Ylds + (n1 << 6) + (tile << 5));
#pragma unroll
                for (int q = 0; q < 8; ++q) {
                    const float4 v = row[q];
#pragma unroll
                    for (int k = 0; k < 2; ++k) {
                        uc[k][4*q+0] = fmaf(cc[k], v.x, uc[k][4*q+0]);
                        uc[k][4*q+1] = fmaf(cc[k], v.y, uc[k][4*q+1]);
                        uc[k][4*q+2] = fmaf(cc[k], v.z, uc[k][4*q+2]);
                        uc[k][4*q+3] = fmaf(cc[k], v.w, uc[k][4*q+3]);
                    }
                }
            }
        }

        // consume this tile's uc with dim-2 coefficients — FULLY unrolled
        // so every uc[k][j] index is a compile-time constant.
#pragma unroll
        for (int j = 0; j < 32; ++j) {
            const int n2 = (tile << 5) + j;
            const float2 tb = tab[n2];
#pragma unroll
            for (int k = 0; k < 2; ++k) {
                const float st = sx2[k] * tb.x - cx2[k] * tb.y;
                const float ct = cx2[k] * tb.x + sx2[k] * tb.y;
                const float s  = (j & 1) ? -s642[k] : s642[k];
                float c = s * ct * __builtin_amdgcn_rcpf(st);
                if (n2 == ns2[k]) c = cf2[k];
                acc[k] = fmaf(c, uc[k][j], acc[k]);
            }
        }
    }

    // ---- subtract rank-1 sine term, normalize, store ----
#pragma unroll
    for (int k = 0; k < 2; ++k) {
        const float r = acc[k] - s641[k] * s642[k] * W;
        out[pbase + (k << 8)] = r * (1.0f / 4096.0f);
    }
}

extern "C" void kernel_launch(void* const* d_in, const int* in_sizes, int n_in,
                              void* d_out, int out_size, void* d_ws, size_t ws_size,
                              hipStream_t stream)
{
    const float* y    = (const float*)d_in[0];   // [32, 64, 64]
    const float* xnew = (const float*)d_in[1];   // [32, 128, 128, 2]
    float* out        = (float*)d_out;           // [32, 128, 128]

    // 32 batches * 32 blocks of 512 points (2 per thread) = 1024 blocks
    fourier_interp_kernel<<<1024, 256, 0, stream>>>(y, xnew, out);
}

// Round 5
// 90.172 us; speedup vs baseline: 1.9151x; 1.4357x over previous
//
#include <hip/hip_runtime.h>
#include <math.h>

#define PI_F  3.14159265358979323846f
#define C64_F 0.99879545620517239271f   // cos(pi/64)
#define S64_F 0.04906767432741801426f   // sin(pi/64)

typedef _Float16 f16x8 __attribute__((ext_vector_type(8)));
typedef float    f32x4 __attribute__((ext_vector_type(4)));

// Fourier (trigonometric) interpolation via MFMA:
//   ynew*4096 = c1^T Y c2 - s641*s642*W      (W = sum (-1)^(n1+n2) Y)
// Stage A (matrix pipe): U[p,n2] = sum_n1 C1[p,n1]*Y[n1,n2] as fp16 hi/lo
//   split GEMM, 3 products (HH + HL + LH); dropped LL term <= 2^-22*sum|C||Y|
//   ~3e-4 abs.  A-operand = Y^T fragments from LDS (A[m=lane&15][k=quad*8+j],
//   one ds_read_b128); B-operand = C1 computed in-register by the owning lane.
//   D layout (col=lane&15=point, row=quad*4+reg=n2): one lane holds one
//   point's 16 U values -> stage B needs 1 dim-2 setup/lane + 2 shuffles.
// Coefficients: c[n] = (-1)^n*s64 * cot(pi*(x-n/64)) via rotation recurrence;
//   nearest-grid entry recomputed from exact (Sterbenz) delta.
// CRITICAL: all register arrays are fully unrolled / constant-indexed
//   (rounds 2-3: any dynamic index -> scratch -> 200+ MB spill traffic).

__global__ __launch_bounds__(256, 3)
void fourier_interp_mfma(const float* __restrict__ y,
                         const float* __restrict__ xnew,
                         float* __restrict__ out)
{
    __shared__ __align__(16) _Float16 Yth[64 * 72];  // Y^T hi, pad 72 (16B-aligned rows)
    __shared__ __align__(16) _Float16 Ytl[64 * 72];  // Y^T lo
    __shared__ float2 tab[64];                       // (cos(pi*n/64), sin(pi*n/64))
    __shared__ float4 S1[256];                       // (sx, cx, s64, cfix) dim 1
    __shared__ float4 S2[256];                       // dim 2
    __shared__ int    NS1[256], NS2[256];            // nearest-grid index
    __shared__ float  Wpart[4];

    const int tid    = threadIdx.x;
    const int batch  = blockIdx.x >> 6;      // 64 blocks per batch
    const int seg    = blockIdx.x & 63;      // 256 points per block
    const int gpbase = (batch << 14) + (seg << 8);

    // ---- stage Y -> transposed f16 hi/lo, fold in signed sum for W ----
    float wsum = 0.0f;
    {
        const float4* srcY = (const float4*)(y + (batch << 12));
#pragma unroll
        for (int i = 0; i < 4; ++i) {
            const int f = tid + (i << 8);          // float4 index 0..1023
            const float4 v = srcY[f];
            const int k = f >> 4;                  // n1 = (4f)>>6
            const int n = (f & 15) << 2;           // n2 base
            _Float16 h;
            h = (_Float16)v.x; Yth[(n+0)*72 + k] = h; Ytl[(n+0)*72 + k] = (_Float16)(v.x - (float)h);
            h = (_Float16)v.y; Yth[(n+1)*72 + k] = h; Ytl[(n+1)*72 + k] = (_Float16)(v.y - (float)h);
            h = (_Float16)v.z; Yth[(n+2)*72 + k] = h; Ytl[(n+2)*72 + k] = (_Float16)(v.z - (float)h);
            h = (_Float16)v.w; Yth[(n+3)*72 + k] = h; Ytl[(n+3)*72 + k] = (_Float16)(v.w - (float)h);
            const float sv = (v.x - v.y) + (v.z - v.w);   // (+,-,+,-) over n2
            wsum += (k & 1) ? -sv : sv;                   // (-1)^n1
        }
    }
#pragma unroll
    for (int off = 32; off > 0; off >>= 1)
        wsum += __shfl_down(wsum, off, 64);
    if ((tid & 63) == 0) Wpart[tid >> 6] = wsum;

    // ---- per-point setups, one point per thread ----
    {
        const float2 xv = ((const float2*)xnew)[gpbase + tid];
        {
            const float x = xv.x;
            float sx, cx; sincosf(PI_F * x, &sx, &cx);
            const float g = x * 64.0f;           // exact
            const float j = rintf(g);
            const float fr = g - j;              // exact (Sterbenz)
            const int  ji = (int)j;
            const float sf = sinf(PI_F * fr);
            const float s64 = (ji & 1) ? -sf : sf;
            const float d = x - j * 0.015625f;   // exact
            const float cf = (fr == 0.0f) ? 64.0f
                                          : sf * cosf(PI_F * d) / sinf(PI_F * d);
            S1[tid]  = make_float4(sx, cx, s64, cf);
            NS1[tid] = ji & 63;
        }
        {
            const float x = xv.y;
            float sx, cx; sincosf(PI_F * x, &sx, &cx);
            const float g = x * 64.0f;
            const float j = rintf(g);
            const float fr = g - j;
            const int  ji = (int)j;
            const float sf = sinf(PI_F * fr);
            const float s64 = (ji & 1) ? -sf : sf;
            const float d = x - j * 0.015625f;
            const float cf = (fr == 0.0f) ? 64.0f
                                          : sf * cosf(PI_F * d) / sinf(PI_F * d);
            S2[tid]  = make_float4(sx, cx, s64, cf);
            NS2[tid] = ji & 63;
        }
    }
    if (tid < 64) {
        float sn, cn;
        sincosf(PI_F * (float)tid * (1.0f / 64.0f), &sn, &cn);
        tab[tid] = make_float2(cn, sn);
    }
    __syncthreads();

    const float W = (Wpart[0] + Wpart[1]) + (Wpart[2] + Wpart[3]);

    const int lane = tid & 63;
    const int wv   = tid >> 6;
    const int quad = lane >> 4;
    const int lrow = lane & 15;

#pragma unroll 1
    for (int mt = 0; mt < 4; ++mt) {
        const int mtbase = (wv << 6) + (mt << 4);   // local point base of this 16-pt tile
        const float4 s1 = S1[mtbase + lrow];        // setup for THIS lane's point
        const int n1fix = NS1[mtbase + lrow];

        // ---- B fragments: C1[p=lrow][n1 = kt*32 + quad*8 + j], fp16 hi/lo ----
        f16x8 bh[2], bl[2];
#pragma unroll
        for (int kt = 0; kt < 2; ++kt) {
            const int n1b = (kt << 5) + (quad << 3);
            const float2 t0 = tab[n1b];
            float st = s1.x * t0.x - s1.y * t0.y;   // sin(pi*(x - n1b/64))
            float ct = s1.y * t0.x + s1.x * t0.y;   // cos(pi*(x - n1b/64))
#pragma unroll
            for (int j = 0; j < 8; ++j) {           // parity(n1) == parity(j)
                const float sgn = (j & 1) ? -s1.z : s1.z;
                float c = sgn * ct * __builtin_amdgcn_rcpf(st);
                c = (n1b + j == n1fix) ? s1.w : c;
                const _Float16 h = (_Float16)c;
                bh[kt][j] = h;
                bl[kt][j] = (_Float16)(c - (float)h);
                if (j < 7) {                         // rotate by pi/64
                    const float st2 = st * C64_F - ct * S64_F;
                    ct = ct * C64_F + st * S64_F;
                    st = st2;
                }
            }
        }

        // ---- MFMA: D[n2_local][p] += Yt_frag * C1_frag, 3-product split ----
        f32x4 acc[4];
#pragma unroll
        for (int nt = 0; nt < 4; ++nt) acc[nt] = (f32x4){0.f, 0.f, 0.f, 0.f};
#pragma unroll
        for (int nt = 0; nt < 4; ++nt) {
#pragma unroll
            for (int kt = 0; kt < 2; ++kt) {
                const int off = ((nt << 4) + lrow) * 72 + (kt << 5) + (quad << 3);
                const f16x8 ah = *(const f16x8*)&Yth[off];   // ds_read_b128
                const f16x8 al = *(const f16x8*)&Ytl[off];
                acc[nt] = __builtin_amdgcn_mfma_f32_16x16x32_f16(ah, bh[kt], acc[nt], 0, 0, 0);
                acc[nt] = __builtin_amdgcn_mfma_f32_16x16x32_f16(ah, bl[kt], acc[nt], 0, 0, 0);
                acc[nt] = __builtin_amdgcn_mfma_f32_16x16x32_f16(al, bh[kt], acc[nt], 0, 0, 0);
            }
        }

        // ---- stage B: lane holds U[p=lrow][n2 = nt*16 + quad*4 + reg] ----
        const float4 s2 = S2[mtbase + lrow];
        const int n2fix = NS2[mtbase + lrow];
        float red = 0.0f;
#pragma unroll
        for (int nt = 0; nt < 4; ++nt) {
#pragma unroll
            for (int reg = 0; reg < 4; ++reg) {
                const int n2 = (nt << 4) + (quad << 2) + reg;  // parity == parity(reg)
                const float2 tb = tab[n2];
                const float st = s2.x * tb.x - s2.y * tb.y;
                const float ct = s2.y * tb.x + s2.x * tb.y;
                const float sgn = (reg & 1) ? -s2.z : s2.z;
                float c = sgn * ct * __builtin_amdgcn_rcpf(st);
                c = (n2 == n2fix) ? s2.w : c;
                red = fmaf(c, acc[nt][reg], red);
            }
        }
        red += __shfl_xor(red, 16, 64);   // reduce across quads (n2 blocks)
        red += __shfl_xor(red, 32, 64);
        if (lane < 16) {                   // writer owns its point's setups
            const float r = red - s1.z * s2.z * W;
            out[gpbase + mtbase + lane] = r * (1.0f / 4096.0f);
        }
    }
}

extern "C" void kernel_launch(void* const* d_in, const int* in_sizes, int n_in,
                              void* d_out, int out_size, void* d_ws, size_t ws_size,
                              hipStream_t stream)
{
    const float* y    = (const float*)d_in[0];   // [32, 64, 64]
    const float* xnew = (const float*)d_in[1];   // [32, 128, 128, 2]
    float* out        = (float*)d_out;           // [32, 128, 128]

    // 32 batches * 64 blocks of 256 points = 2048 blocks
    fourier_interp_mfma<<<2048, 256, 0, stream>>>(y, xnew, out);
}

// Round 6
// 86.972 us; speedup vs baseline: 1.9856x; 1.0368x over previous
//
#include <hip/hip_runtime.h>
#include <math.h>

#define PI_F  3.14159265358979323846f
#define C64_F 0.99879545620517239271f   // cos(pi/64)
#define S64_F 0.04906767432741801426f   // sin(pi/64)

typedef _Float16 f16x8 __attribute__((ext_vector_type(8)));
typedef float    f32x4 __attribute__((ext_vector_type(4)));

// v_sin_f32 / v_cos_f32 take REVOLUTIONS: sin(pi*x) = v_sin(0.5*x).
// Every trig argument in this kernel is already in [-0.5, 0.5] revolutions,
// so NO range reduction is needed anywhere.
__device__ __forceinline__ float sinpi_hw(float x) { return __builtin_amdgcn_sinf(0.5f * x); }
__device__ __forceinline__ float cospi_hw(float x) { return __builtin_amdgcn_cosf(0.5f * x); }

// Fourier (trigonometric) interpolation via MFMA:
//   ynew*4096 = c1^T Y c2 - s641*s642*W      (W = sum (-1)^(n1+n2) Y)
// Stage A (matrix pipe): U[p,n2] = sum_n1 C1[p,n1]*Y[n1,n2] as fp16 hi/lo
//   split GEMM, 3 products (HH + HL + LH).
//   A-operand = Y^T fragments: mt-INVARIANT -> hoisted to registers once
//   (round 5 re-read them 4x from LDS on a 4-bank-step stride: 4.2M
//   conflict cycles). B-operand = C1 computed in-register by owning lane.
// Coefficients: c[n] = (-1)^n*s64 * cot(pi*(x-n/64)) via rotation recurrence;
//   nearest-grid entry recomputed from exact (Sterbenz) delta.
// CRITICAL: all register arrays fully unrolled / constant-indexed
//   (rounds 2-3: any dynamic index -> scratch -> 200+ MB spill traffic).

__global__ __launch_bounds__(256, 3)
void fourier_interp_mfma(const float* __restrict__ y,
                         const float* __restrict__ xnew,
                         float* __restrict__ out)
{
    __shared__ __align__(16) _Float16 Yth[64 * 72];  // Y^T hi, pad 72
    __shared__ __align__(16) _Float16 Ytl[64 * 72];  // Y^T lo
    __shared__ float2 tab[64];                       // (cos(pi*n/64), sin(pi*n/64))
    __shared__ float4 S1[256];                       // (sx, cx, s64, cfix) dim 1
    __shared__ float4 S2[256];                       // dim 2
    __shared__ int    NS1[256], NS2[256];            // nearest-grid index
    __shared__ float  Wpart[4];

    const int tid    = threadIdx.x;
    const int batch  = blockIdx.x >> 6;      // 64 blocks per batch
    const int seg    = blockIdx.x & 63;      // 256 points per block
    const int gpbase = (batch << 14) + (seg << 8);

    // ---- stage Y -> transposed f16 hi/lo, fold in signed sum for W ----
    float wsum = 0.0f;
    {
        const float4* srcY = (const float4*)(y + (batch << 12));
#pragma unroll
        for (int i = 0; i < 4; ++i) {
            const int f = tid + (i << 8);          // float4 index 0..1023
            const float4 v = srcY[f];
            const int k = f >> 4;                  // n1
            const int n = (f & 15) << 2;           // n2 base
            _Float16 h;
            h = (_Float16)v.x; Yth[(n+0)*72 + k] = h; Ytl[(n+0)*72 + k] = (_Float16)(v.x - (float)h);
            h = (_Float16)v.y; Yth[(n+1)*72 + k] = h; Ytl[(n+1)*72 + k] = (_Float16)(v.y - (float)h);
            h = (_Float16)v.z; Yth[(n+2)*72 + k] = h; Ytl[(n+2)*72 + k] = (_Float16)(v.z - (float)h);
            h = (_Float16)v.w; Yth[(n+3)*72 + k] = h; Ytl[(n+3)*72 + k] = (_Float16)(v.w - (float)h);
            const float sv = (v.x - v.y) + (v.z - v.w);   // (+,-,+,-) over n2
            wsum += (k & 1) ? -sv : sv;                   // (-1)^n1
        }
    }
#pragma unroll
    for (int off = 32; off > 0; off >>= 1)
        wsum += __shfl_down(wsum, off, 64);
    if ((tid & 63) == 0) Wpart[tid >> 6] = wsum;

    // ---- per-point setups, one point per thread (HW trig, no libm) ----
    {
        const float2 xv = ((const float2*)xnew)[gpbase + tid];
        {
            const float x = xv.x;
            const float sx = sinpi_hw(x), cx = cospi_hw(x);
            const float g = x * 64.0f;           // exact
            const float j = rintf(g);
            const float fr = g - j;              // exact (Sterbenz)
            const int  ji = (int)j;
            const float sf = sinpi_hw(fr);
            const float s64 = (ji & 1) ? -sf : sf;
            const float d = x - j * 0.015625f;   // exact
            const float cf = (fr == 0.0f) ? 64.0f
                : sf * cospi_hw(d) * __builtin_amdgcn_rcpf(sinpi_hw(d));
            S1[tid]  = make_float4(sx, cx, s64, cf);
            NS1[tid] = ji & 63;
        }
        {
            const float x = xv.y;
            const float sx = sinpi_hw(x), cx = cospi_hw(x);
            const float g = x * 64.0f;
            const float j = rintf(g);
            const float fr = g - j;
            const int  ji = (int)j;
            const float sf = sinpi_hw(fr);
            const float s64 = (ji & 1) ? -sf : sf;
            const float d = x - j * 0.015625f;
            const float cf = (fr == 0.0f) ? 64.0f
                : sf * cospi_hw(d) * __builtin_amdgcn_rcpf(sinpi_hw(d));
            S2[tid]  = make_float4(sx, cx, s64, cf);
            NS2[tid] = ji & 63;
        }
    }
    if (tid < 64)
        tab[tid] = make_float2(cospi_hw((float)tid * (1.0f / 64.0f)),
                               sinpi_hw((float)tid * (1.0f / 64.0f)));
    __syncthreads();

    const float W = (Wpart[0] + Wpart[1]) + (Wpart[2] + Wpart[3]);

    const int lane = tid & 63;
    const int wv   = tid >> 6;
    const int quad = lane >> 4;
    const int lrow = lane & 15;

    // ---- hoist A-operand (Y^T) fragments: mt-invariant, read LDS ONCE ----
    f16x8 Ah[4][2], Al[4][2];
#pragma unroll
    for (int nt = 0; nt < 4; ++nt)
#pragma unroll
        for (int kt = 0; kt < 2; ++kt) {
            const int off = ((nt << 4) + lrow) * 72 + (kt << 5) + (quad << 3);
            Ah[nt][kt] = *(const f16x8*)&Yth[off];   // ds_read_b128
            Al[nt][kt] = *(const f16x8*)&Ytl[off];
        }

#pragma unroll 1
    for (int mt = 0; mt < 4; ++mt) {
        const int mtbase = (wv << 6) + (mt << 4);   // local point base of tile
        const float4 s1 = S1[mtbase + lrow];        // setup for THIS lane's point
        const int n1fix = NS1[mtbase + lrow];

        f32x4 acc[4];
#pragma unroll
        for (int nt = 0; nt < 4; ++nt) acc[nt] = (f32x4){0.f, 0.f, 0.f, 0.f};

        // ---- per kt: build B fragment (C1 hi/lo), then MFMA over nt ----
#pragma unroll
        for (int kt = 0; kt < 2; ++kt) {
            const int n1b = (kt << 5) + (quad << 3);
            const float2 t0 = tab[n1b];
            float st = s1.x * t0.x - s1.y * t0.y;   // sin(pi*(x - n1b/64))
            float ct = s1.y * t0.x + s1.x * t0.y;   // cos(pi*(x - n1b/64))
            f16x8 bh, bl;
#pragma unroll
            for (int j = 0; j < 8; ++j) {           // parity(n1) == parity(j)
                const float sgn = (j & 1) ? -s1.z : s1.z;
                float c = sgn * ct * __builtin_amdgcn_rcpf(st);
                c = (n1b + j == n1fix) ? s1.w : c;
                const _Float16 h = (_Float16)c;
                bh[j] = h;
                bl[j] = (_Float16)(c - (float)h);
                if (j < 7) {                         // rotate by pi/64
                    const float st2 = st * C64_F - ct * S64_F;
                    ct = ct * C64_F + st * S64_F;
                    st = st2;
                }
            }
#pragma unroll
            for (int nt = 0; nt < 4; ++nt) {
                acc[nt] = __builtin_amdgcn_mfma_f32_16x16x32_f16(Ah[nt][kt], bh, acc[nt], 0, 0, 0);
                acc[nt] = __builtin_amdgcn_mfma_f32_16x16x32_f16(Ah[nt][kt], bl, acc[nt], 0, 0, 0);
                acc[nt] = __builtin_amdgcn_mfma_f32_16x16x32_f16(Al[nt][kt], bh, acc[nt], 0, 0, 0);
            }
        }

        // ---- stage B: lane holds U[p=lrow][n2 = nt*16 + quad*4 + reg] ----
        const float4 s2 = S2[mtbase + lrow];
        const int n2fix = NS2[mtbase + lrow];
        float red = 0.0f;
#pragma unroll
        for (int nt = 0; nt < 4; ++nt) {
            const int n2b = (nt << 4) + (quad << 2);
            const float2 tb = tab[n2b];
            float st = s2.x * tb.x - s2.y * tb.y;
            float ct = s2.y * tb.x + s2.x * tb.y;
#pragma unroll
            for (int reg = 0; reg < 4; ++reg) {      // parity(n2) == parity(reg)
                const float sgn = (reg & 1) ? -s2.z : s2.z;
                float c = sgn * ct * __builtin_amdgcn_rcpf(st);
                c = (n2b + reg == n2fix) ? s2.w : c;
                red = fmaf(c, acc[nt][reg], red);
                if (reg < 3) {                        // rotate by pi/64
                    const float st2 = st * C64_F - ct * S64_F;
                    ct = ct * C64_F + st * S64_F;
                    st = st2;
                }
            }
        }
        red += __shfl_xor(red, 16, 64);   // reduce across quads (n2 blocks)
        red += __shfl_xor(red, 32, 64);
        if (lane < 16) {                   // writer owns its point's setups
            const float r = red - s1.z * s2.z * W;
            out[gpbase + mtbase + lane] = r * (1.0f / 4096.0f);
        }
    }
}

extern "C" void kernel_launch(void* const* d_in, const int* in_sizes, int n_in,
                              void* d_out, int out_size, void* d_ws, size_t ws_size,
                              hipStream_t stream)
{
    const float* y    = (const float*)d_in[0];   // [32, 64, 64]
    const float* xnew = (const float*)d_in[1];   // [32, 128, 128, 2]
    float* out        = (float*)d_out;           // [32, 128, 128]

    // 32 batches * 64 blocks of 256 points = 2048 blocks
    fourier_interp_mfma<<<2048, 256, 0, stream>>>(y, xnew, out);
}

// Round 7
// 80.890 us; speedup vs baseline: 2.1349x; 1.0752x over previous
//
#include <hip/hip_runtime.h>
#include <math.h>

#define PI_F  3.14159265358979323846f
#define C64_F 0.99879545620517239271f   // cos(pi/64)
#define S64_F 0.04906767432741801426f   // sin(pi/64)

typedef _Float16 f16x8 __attribute__((ext_vector_type(8)));
typedef float    f32x4 __attribute__((ext_vector_type(4)));

// v_sin_f32 / v_cos_f32 take REVOLUTIONS: sin(pi*x) = v_sin(0.5*x).
// Every trig argument here is already in [-0.5, 0.5] revolutions -> no
// range reduction anywhere.
__device__ __forceinline__ float sinpi_hw(float x) { return __builtin_amdgcn_sinf(0.5f * x); }
__device__ __forceinline__ float cospi_hw(float x) { return __builtin_amdgcn_cosf(0.5f * x); }

// Fourier (trigonometric) interpolation via MFMA:
//   ynew*4096 = c1^T Y c2 - s641*s642*W      (W = sum (-1)^(n1+n2) Y)
// Stage A (matrix pipe): U[p,n2] = sum_n1 C1[p,n1]*Y[n1,n2], SINGLE f16
//   product (round 7: hi/lo split dropped — error bound ~1e-2 abs, well
//   under the 8.7e-2 threshold; rounds 5/6 showed the split moved absmax
//   by exactly 0). c2 side stays full fp32.
//   A-operand = Y^T fragments, mt-invariant, hoisted to registers once.
//   B-operand = C1 computed in-register by the owning lane.
// Coefficients: c[n] = (-1)^n*s64 * cot(pi*(x-n/64)) via rotation
//   recurrence; nearest-grid entry from exact (Sterbenz) delta.
// 512 points/block (8 mt-tiles/wave) amortizes staging/W/A-hoist 2x.
// CRITICAL: all register arrays fully unrolled / constant-indexed
//   (rounds 2-3: any dynamic index -> scratch -> 200+ MB spill traffic).

__global__ __launch_bounds__(256, 3)
void fourier_interp_mfma(const float* __restrict__ y,
                         const float* __restrict__ xnew,
                         float* __restrict__ out)
{
    __shared__ __align__(16) _Float16 Yth[64 * 72];  // Y^T f16, pad 72
    __shared__ float2 tab[64];                       // (cos(pi*n/64), sin(pi*n/64))
    __shared__ float4 S1[512];                       // (sx, cx, s64, cfix) dim 1
    __shared__ float4 S2[512];                       // dim 2
    __shared__ int    NS1[512], NS2[512];            // nearest-grid index
    __shared__ float  Wpart[4];

    const int tid    = threadIdx.x;
    const int batch  = blockIdx.x >> 5;      // 32 blocks per batch
    const int seg    = blockIdx.x & 31;      // 512 points per block
    const int gpbase = (batch << 14) + (seg << 9);

    // ---- stage Y -> transposed f16, fold in signed sum for W ----
    float wsum = 0.0f;
    {
        const float4* srcY = (const float4*)(y + (batch << 12));
#pragma unroll
        for (int i = 0; i < 4; ++i) {
            const int f = tid + (i << 8);          // float4 index 0..1023
            const float4 v = srcY[f];
            const int k = f >> 4;                  // n1
            const int n = (f & 15) << 2;           // n2 base
            Yth[(n+0)*72 + k] = (_Float16)v.x;
            Yth[(n+1)*72 + k] = (_Float16)v.y;
            Yth[(n+2)*72 + k] = (_Float16)v.z;
            Yth[(n+3)*72 + k] = (_Float16)v.w;
            const float sv = (v.x - v.y) + (v.z - v.w);   // (+,-,+,-) over n2
            wsum += (k & 1) ? -sv : sv;                   // (-1)^n1
        }
    }
#pragma unroll
    for (int off = 32; off > 0; off >>= 1)
        wsum += __shfl_down(wsum, off, 64);
    if ((tid & 63) == 0) Wpart[tid >> 6] = wsum;

    // ---- per-point setups, two points per thread (HW trig, no libm) ----
#pragma unroll
    for (int sp = 0; sp < 2; ++sp) {
        const int idx = tid + (sp << 8);
        const float2 xv = ((const float2*)xnew)[gpbase + idx];
        {
            const float x = xv.x;
            const float sx = sinpi_hw(x), cx = cospi_hw(x);
            const float g = x * 64.0f;           // exact
            const float j = rintf(g);
            const float fr = g - j;              // exact (Sterbenz)
            const int  ji = (int)j;
            const float sf = sinpi_hw(fr);
            const float s64 = (ji & 1) ? -sf : sf;
            const float d = x - j * 0.015625f;   // exact
            const float cf = (fr == 0.0f) ? 64.0f
                : sf * cospi_hw(d) * __builtin_amdgcn_rcpf(sinpi_hw(d));
            S1[idx]  = make_float4(sx, cx, s64, cf);
            NS1[idx] = ji & 63;
        }
        {
            const float x = xv.y;
            const float sx = sinpi_hw(x), cx = cospi_hw(x);
            const float g = x * 64.0f;
            const float j = rintf(g);
            const float fr = g - j;
            const int  ji = (int)j;
            const float sf = sinpi_hw(fr);
            const float s64 = (ji & 1) ? -sf : sf;
            const float d = x - j * 0.015625f;
            const float cf = (fr == 0.0f) ? 64.0f
                : sf * cospi_hw(d) * __builtin_amdgcn_rcpf(sinpi_hw(d));
            S2[idx]  = make_float4(sx, cx, s64, cf);
            NS2[idx] = ji & 63;
        }
    }
    if (tid < 64)
        tab[tid] = make_float2(cospi_hw((float)tid * (1.0f / 64.0f)),
                               sinpi_hw((float)tid * (1.0f / 64.0f)));
    __syncthreads();

    const float W = (Wpart[0] + Wpart[1]) + (Wpart[2] + Wpart[3]);

    const int lane = tid & 63;
    const int wv   = tid >> 6;
    const int quad = lane >> 4;
    const int lrow = lane & 15;

    // ---- hoist A-operand (Y^T) fragments: mt-invariant, read LDS ONCE ----
    f16x8 Ah[4][2];
#pragma unroll
    for (int nt = 0; nt < 4; ++nt)
#pragma unroll
        for (int kt = 0; kt < 2; ++kt) {
            const int off = ((nt << 4) + lrow) * 72 + (kt << 5) + (quad << 3);
            Ah[nt][kt] = *(const f16x8*)&Yth[off];   // ds_read_b128
        }

    // ---- 8 tiles of 16 points per wave ----
#pragma unroll 1
    for (int mt = 0; mt < 8; ++mt) {
        const int mtbase = (wv << 7) + (mt << 4);   // local point base of tile
        const float4 s1 = S1[mtbase + lrow];        // setup for THIS lane's point
        const int n1fix = NS1[mtbase + lrow];

        f32x4 acc[4];
#pragma unroll
        for (int nt = 0; nt < 4; ++nt) acc[nt] = (f32x4){0.f, 0.f, 0.f, 0.f};

        // ---- per kt: build B fragment (C1 f16), then MFMA over nt ----
#pragma unroll
        for (int kt = 0; kt < 2; ++kt) {
            const int n1b = (kt << 5) + (quad << 3);
            const float2 t0 = tab[n1b];
            float st = s1.x * t0.x - s1.y * t0.y;   // sin(pi*(x - n1b/64))
            float ct = s1.y * t0.x + s1.x * t0.y;   // cos(pi*(x - n1b/64))
            f16x8 bh;
#pragma unroll
            for (int j = 0; j < 8; ++j) {           // parity(n1) == parity(j)
                const float sgn = (j & 1) ? -s1.z : s1.z;
                float c = sgn * ct * __builtin_amdgcn_rcpf(st);
                c = (n1b + j == n1fix) ? s1.w : c;
                bh[j] = (_Float16)c;
                if (j < 7) {                         // rotate by pi/64
                    const float st2 = st * C64_F - ct * S64_F;
                    ct = ct * C64_F + st * S64_F;
                    st = st2;
                }
            }
#pragma unroll
            for (int nt = 0; nt < 4; ++nt)
                acc[nt] = __builtin_amdgcn_mfma_f32_16x16x32_f16(Ah[nt][kt], bh, acc[nt], 0, 0, 0);
        }

        // ---- stage B: lane holds U[p=lrow][n2 = nt*16 + quad*4 + reg] ----
        const float4 s2 = S2[mtbase + lrow];
        const int n2fix = NS2[mtbase + lrow];
        float red = 0.0f;
#pragma unroll
        for (int nt = 0; nt < 4; ++nt) {
            const int n2b = (nt << 4) + (quad << 2);
            const float2 tb = tab[n2b];
            float st = s2.x * tb.x - s2.y * tb.y;
            float ct = s2.y * tb.x + s2.x * tb.y;
#pragma unroll
            for (int reg = 0; reg < 4; ++reg) {      // parity(n2) == parity(reg)
                const float sgn = (reg & 1) ? -s2.z : s2.z;
                float c = sgn * ct * __builtin_amdgcn_rcpf(st);
                c = (n2b + reg == n2fix) ? s2.w : c;
                red = fmaf(c, acc[nt][reg], red);
                if (reg < 3) {                        // rotate by pi/64
                    const float st2 = st * C64_F - ct * S64_F;
                    ct = ct * C64_F + st * S64_F;
                    st = st2;
                }
            }
        }
        red += __shfl_xor(red, 16, 64);   // reduce across quads (n2 blocks)
        red += __shfl_xor(red, 32, 64);
        if (lane < 16) {                   // writer owns its point's setups
            const float r = red - s1.z * s2.z * W;
            out[gpbase + mtbase + lane] = r * (1.0f / 4096.0f);
        }
    }
}

extern "C" void kernel_launch(void* const* d_in, const int* in_sizes, int n_in,
                              void* d_out, int out_size, void* d_ws, size_t ws_size,
                              hipStream_t stream)
{
    const float* y    = (const float*)d_in[0];   // [32, 64, 64]
    const float* xnew = (const float*)d_in[1];   // [32, 128, 128, 2]
    float* out        = (float*)d_out;           // [32, 128, 128]

    // 32 batches * 32 blocks of 512 points = 1024 blocks
    fourier_interp_mfma<<<1024, 256, 0, stream>>>(y, xnew, out);
}